// Round 5
// baseline (749.303 us; speedup 1.0000x reference)
//
#include <hip/hip_runtime.h>

#define Bq 2
#define Lq 2048
#define Hq 16
#define Eq 64
#define HE (Hq * Eq)   // 1024 floats between consecutive l for fixed (h)

// LDS layout for compute kernel (floats unless noted), total 74,752 B -> 2 wg/CU:
//   Qs  [64][68]          17,408 B
//   KVs [5120]            20,480 B   K rounds: [256 keys][20]; V rounds: [64][16 f4] XOR-swizzled
//   red [512]              2,048 B
//   Sp  ushort[64][272]   34,816 B   normalized p, bf16, permuted cols
#define QS_STRIDE 68
#define KV_OFF    4352
#define RED_OFF   9472
#define SP_OFF    9984
#define SP_STRIDE 272

typedef float nfloat4 __attribute__((ext_vector_type(4)));

__device__ __forceinline__ void nt_store4(float* p, float x, float y, float z, float w) {
    nfloat4 v = {x, y, z, w};
    __builtin_nontemporal_store(v, (nfloat4*)p);
}

__device__ __forceinline__ unsigned short f2bf(float x) {
    unsigned u = __float_as_uint(x);
    return (unsigned short)((u + 0x7fffu + ((u >> 16) & 1u)) >> 16);  // RNE
}
__device__ __forceinline__ float bf2f(unsigned short s) {
    return __uint_as_float(((unsigned)s) << 16);
}

// ---------------- Kernel A: pure-store zero fill of off-diagonal attn ----------------
// attn is [B*H*L = 65536 rows][2048 cols]. Each wg owns 32 consecutive rows (one qb,
// wg-uniform). Per row: 448 off-diagonal float4 columns. 2048 wgs x 256 thr, 56 f4/thr.
// This mirrors the fillBuffer structure that measures 6.2 TB/s on this buffer.
__global__ __launch_bounds__(256)
void zero_offdiag(float* __restrict__ attn)
{
    const int w = blockIdx.x;
    const int t = threadIdx.x;
    const size_t row0 = (size_t)w * 32;
    const int l0   = (int)(row0 & 2047);
    const int qb64 = (l0 >> 8) * 64;          // diagonal hole start (f4 units), wg-uniform
    float* base = attn + row0 * Lq;

    #pragma unroll
    for (int i = 0; i < 56; ++i) {
        int f = i * 256 + t;                  // [0, 14336)
        int r = f / 448;                      // 0..31 (magic-mul)
        int j = f - r * 448;
        int c4 = (j < qb64) ? j : j + 64;     // skip the 64-f4 diagonal hole
        nt_store4(base + (size_t)r * Lq + c4 * 4, 0.f, 0.f, 0.f, 0.f);
    }
}

// ---------------- Kernel B: compute + diagonal attn + output ----------------
__global__ __launch_bounds__(256, 2)
void sparse_attn(const float* __restrict__ qp, const float* __restrict__ kp,
                 const float* __restrict__ vp, float* __restrict__ outp)
{
    extern __shared__ float smem[];
    float* Qs  = smem;
    float* KVs = smem + KV_OFF;
    float* red = smem + RED_OFF;
    unsigned short* Sp = (unsigned short*)(smem + SP_OFF);

    const int w3  = blockIdx.x;
    const int sub = w3 & 3, qb = (w3 >> 2) & 7, h = (w3 >> 5) & 15, b = w3 >> 9;
    const int R0  = qb * 256 + sub * 64;

    const int t = threadIdx.x;
    const int wv = t >> 6, lane = t & 63, rg = lane & 7, cg = lane >> 3;

    const float* qbase = qp + ((size_t)(b * Lq + R0) * Hq + h) * Eq;
    const float* kbase = kp + ((size_t)(b * Lq + qb * 256) * Hq + h) * Eq;
    const float* vbase = vp + ((size_t)(b * Lq + qb * 256) * Hq + h) * Eq;
    float* attn   = outp + (size_t)Bq * Lq * Hq * Eq;
    float* ablock = attn + ((size_t)(b * Hq + h) * Lq + R0) * Lq;

    // ---- stage Q (all 64 dims) + K round 0 (dims 0..15) ----
    #pragma unroll
    for (int i = 0; i < 4; ++i) {
        int idx = i * 256 + t, row = idx >> 4, e4 = idx & 15;
        *(float4*)&Qs[row * QS_STRIDE + e4 * 4] =
            *(const float4*)(qbase + (size_t)row * HE + e4 * 4);
    }
    #pragma unroll
    for (int i = 0; i < 4; ++i) {
        int idx = i * 256 + t, key = idx >> 2, e4 = idx & 3;
        *(float4*)&KVs[key * 20 + e4 * 4] =
            *(const float4*)(kbase + (size_t)key * HE + e4 * 4);
    }
    __syncthreads();

    // ---- P1: QK^T, lane tile 8 rows (rg+8i) x 8 cols (wv*64+cg+8j), 4 dim-rounds ----
    float sc[8][8];
    #pragma unroll
    for (int i = 0; i < 8; ++i)
        #pragma unroll
        for (int j = 0; j < 8; ++j) sc[i][j] = 0.f;

    for (int rd = 0; rd < 4; ++rd) {
        #pragma unroll
        for (int kc = 0; kc < 4; ++kc) {
            float4 qf[8], kf[8];
            #pragma unroll
            for (int i = 0; i < 8; ++i)
                qf[i] = *(float4*)&Qs[(rg + 8 * i) * QS_STRIDE + rd * 16 + kc * 4];
            #pragma unroll
            for (int j = 0; j < 8; ++j)
                kf[j] = *(float4*)&KVs[(wv * 64 + cg + 8 * j) * 20 + kc * 4];
            #pragma unroll
            for (int i = 0; i < 8; ++i)
                #pragma unroll
                for (int j = 0; j < 8; ++j)
                    sc[i][j] = fmaf(qf[i].x, kf[j].x,
                               fmaf(qf[i].y, kf[j].y,
                               fmaf(qf[i].z, kf[j].z,
                               fmaf(qf[i].w, kf[j].w, sc[i][j]))));
        }
        if (rd < 3) {
            __syncthreads();
            #pragma unroll
            for (int i = 0; i < 4; ++i) {
                int idx = i * 256 + t, key = idx >> 2, e4 = idx & 3;
                *(float4*)&KVs[key * 20 + e4 * 4] =
                    *(const float4*)(kbase + (size_t)key * HE + (rd + 1) * 16 + e4 * 4);
            }
            __syncthreads();
        }
    }

    // ---- softmax fully in registers + tiny LDS cross-wave exchange ----
    float mrow[8];
    #pragma unroll
    for (int i = 0; i < 8; ++i) {
        float m = sc[i][0];
        #pragma unroll
        for (int j = 1; j < 8; ++j) m = fmaxf(m, sc[i][j]);
        m = fmaxf(m, __shfl_xor(m, 8));
        m = fmaxf(m, __shfl_xor(m, 16));
        m = fmaxf(m, __shfl_xor(m, 32));
        mrow[i] = m;
    }
    if (cg == 0) {
        #pragma unroll
        for (int i = 0; i < 8; ++i) red[wv * 64 + rg + 8 * i] = mrow[i];
    }
    __syncthreads();   // b1: mred visible; all waves done with K tile

    // stage V round 0 into KVs (dead K region), overlapping the exp work below
    #pragma unroll
    for (int i = 0; i < 4; ++i) {
        int idx = i * 256 + t, k63 = idx >> 4, e4 = idx & 15;
        *(float4*)&KVs[(k63 * 16 + (e4 ^ (k63 >> 3))) * 4] =
            *(const float4*)(vbase + (size_t)k63 * HE + e4 * 4);
    }

    float lrow[8];
    #pragma unroll
    for (int i = 0; i < 8; ++i) {
        int r = rg + 8 * i;
        float m = fmaxf(fmaxf(red[r], red[64 + r]), fmaxf(red[128 + r], red[192 + r]));
        float l = 0.f;
        #pragma unroll
        for (int j = 0; j < 8; ++j) {
            float e = __expf(sc[i][j] - m);
            sc[i][j] = e;
            l += e;
        }
        l += __shfl_xor(l, 8);
        l += __shfl_xor(l, 16);
        l += __shfl_xor(l, 32);
        lrow[i] = l;
    }
    if (cg == 0) {
        #pragma unroll
        for (int i = 0; i < 8; ++i) red[256 + wv * 64 + rg + 8 * i] = lrow[i];
    }
    __syncthreads();   // b2: lred + V0 visible

    // normalize in-register, pack bf16, write Sp (contiguous b128 per row)
    #pragma unroll
    for (int i = 0; i < 8; ++i) {
        int r = rg + 8 * i;
        float linv = 1.0f / (red[256 + r] + red[320 + r] + red[384 + r] + red[448 + r]);
        unsigned u0 = (unsigned)f2bf(sc[i][0] * linv) | ((unsigned)f2bf(sc[i][1] * linv) << 16);
        unsigned u1 = (unsigned)f2bf(sc[i][2] * linv) | ((unsigned)f2bf(sc[i][3] * linv) << 16);
        unsigned u2 = (unsigned)f2bf(sc[i][4] * linv) | ((unsigned)f2bf(sc[i][5] * linv) << 16);
        unsigned u3 = (unsigned)f2bf(sc[i][6] * linv) | ((unsigned)f2bf(sc[i][7] * linv) << 16);
        *(uint4*)&Sp[r * SP_STRIDE + wv * 64 + cg * 8] = make_uint4(u0, u1, u2, u3);
    }
    __syncthreads();   // b3: Sp visible

    // ---- P3: PV. wave wv owns rows 16wv..+15; lane tile 4 rows x 4 dims ----
    const int r4 = lane & 3, d4 = lane >> 2;
    float4 acc[4];
    #pragma unroll
    for (int i = 0; i < 4; ++i) acc[i] = make_float4(0.f, 0.f, 0.f, 0.f);

    for (int kb = 0; kb < 4; ++kb) {
        if (kb) {
            __syncthreads();
            #pragma unroll
            for (int i = 0; i < 4; ++i) {
                int idx = i * 256 + t, k63 = idx >> 4, e4 = idx & 15;
                *(float4*)&KVs[(k63 * 16 + (e4 ^ (k63 >> 3))) * 4] =
                    *(const float4*)(vbase + (size_t)(kb * 64 + k63) * HE + e4 * 4);
            }
            __syncthreads();
        }
        #pragma unroll
        for (int c = 0; c < 8; ++c) {
            float pv[4][8];
            #pragma unroll
            for (int i = 0; i < 4; ++i) {
                int row = 16 * wv + r4 + 4 * i;
                uint4 pw = *(uint4*)&Sp[row * SP_STRIDE + kb * 64 + c * 8];
                pv[i][0] = __uint_as_float(pw.x << 16);
                pv[i][1] = __uint_as_float(pw.x & 0xffff0000u);
                pv[i][2] = __uint_as_float(pw.y << 16);
                pv[i][3] = __uint_as_float(pw.y & 0xffff0000u);
                pv[i][4] = __uint_as_float(pw.z << 16);
                pv[i][5] = __uint_as_float(pw.z & 0xffff0000u);
                pv[i][6] = __uint_as_float(pw.w << 16);
                pv[i][7] = __uint_as_float(pw.w & 0xffff0000u);
            }
            #pragma unroll
            for (int k = 0; k < 8; ++k) {
                float4 vv = *(float4*)&KVs[((c + 8 * k) * 16 + (d4 ^ k)) * 4];
                #pragma unroll
                for (int i = 0; i < 4; ++i) {
                    acc[i].x = fmaf(pv[i][k], vv.x, acc[i].x);
                    acc[i].y = fmaf(pv[i][k], vv.y, acc[i].y);
                    acc[i].z = fmaf(pv[i][k], vv.z, acc[i].z);
                    acc[i].w = fmaf(pv[i][k], vv.w, acc[i].w);
                }
            }
        }
    }

    // ---- epilogue: output + diagonal attn block only (zeros handled by kernel A) ----
    #pragma unroll
    for (int i = 0; i < 4; ++i) {
        int row = 16 * wv + r4 + 4 * i;
        float* dst = outp + ((size_t)(b * Lq + R0 + row) * Hq + h) * Eq + d4 * 4;
        nt_store4(dst, acc[i].x, acc[i].y, acc[i].z, acc[i].w);
    }

    #pragma unroll 4
    for (int i = 0; i < 16; ++i) {
        int idx = i * 256 + t, row = idx >> 6, c4 = idx & 63, c = c4 * 4;
        int basep = row * SP_STRIDE + (c & 0xC0) + ((c >> 3) & 7);
        int c7 = c & 7;   // 0 or 4
        nt_store4(ablock + (size_t)row * Lq + qb * 256 + c,
                  bf2f(Sp[basep + (c7 + 0) * 8]),
                  bf2f(Sp[basep + (c7 + 1) * 8]),
                  bf2f(Sp[basep + (c7 + 2) * 8]),
                  bf2f(Sp[basep + (c7 + 3) * 8]));
    }
}

extern "C" void kernel_launch(void* const* d_in, const int* in_sizes, int n_in,
                              void* d_out, int out_size, void* d_ws, size_t ws_size,
                              hipStream_t stream) {
    const float* q = (const float*)d_in[0];
    const float* k = (const float*)d_in[1];
    const float* v = (const float*)d_in[2];
    float* out  = (float*)d_out;
    float* attn = out + (size_t)Bq * Lq * Hq * Eq;

    const size_t lds_bytes = SP_OFF * sizeof(float) + 64 * SP_STRIDE * sizeof(unsigned short); // 74,752
    (void)hipFuncSetAttribute((const void*)sparse_attn,
                              hipFuncAttributeMaxDynamicSharedMemorySize,
                              (int)lds_bytes);

    // A: pure streaming zero-fill of the off-diagonal 448 MiB (fill-kernel shape)
    hipLaunchKernelGGL(zero_offdiag, dim3(2048), dim3(256), 0, stream, attn);
    // B: compute + diagonal + output
    hipLaunchKernelGGL(sparse_attn, dim3(Bq * Hq * 8 * 4), dim3(256), lds_bytes, stream,
                       q, k, v, out);
}